// Round 4
// baseline (114.894 us; speedup 1.0000x reference)
//
#include <hip/hip_runtime.h>
#include <stdint.h>

// Simple exponential smoothing: level_t = (1-a)*level_{t-1} + a*y_t,
// level_0 = y_0 pinned via global initial carry s_{-1} = y_0.
// out[t] = level_t for t in [0, n-2].
//
// R12 = R11 (windowed-carry + LDS-everything marshalling, 113.7us total,
// emit ~25us) + ADAPTIVE HALO:
//   R11 read a fixed 4096-elem halo per block = 32MB of reads. The needed
//   window is W = ln(eps)/ln(1-a): ~30 elems for typical alpha~0.5. Compute
//   W on-device (logf, block-uniform, target e^-19.5, clamp [16,4096]);
//   only threads whose halo segment overlaps the last W elements load.
//   Halo traffic 32MB -> ~0.5MB. Truncation <= max(e^-19.5, 1e-8)*|level|,
//   ~3 orders under the fp32-drift absmax (bit-identical 2^-10 across
//   slow/fast rounds). Also: halo wave-totals in separate LDS slots
//   (hwa/hwb), fold moved after the common barrier -> one fewer barrier.
//   Ledger (fills ~85us fixed): R8 41.5 | R9 57 (reg-spill) | R10 118
//   (store RMW + L2-miss re-read) | R11 28.7 (agg 2 + emit 25).
//   emit floor = 128MB stream ~ 20.3us.
// Bans (measured): in-kernel grid sync (R2 ~80us, R7 ~125us — cross-XCD
// coherence), coop launch (R4: graph-capture reject), per-thread direct
// float4 stores of contiguous segments (R10: L2 RMW inflation), bulk
// register tile cache (R9: scratch spill).
//
// Affine pairs (a,b): s_out = a*s_in + b.
// combine(earlier=(a1,b1), later=(a2,b2)) = (a1*a2, a2*b1 + b2).

#define BLOCK 256
#define SEG   32                  // elements per thread
#define VPT   (SEG / 4)           // 8 float4 per thread
#define CHUNK (BLOCK * SEG)       // 8192 elements per block
#define NF4   (CHUNK / 4)         // 2048 float4 slots in LDS
#define HALO  4096                // max windowed-carry history length
#define HSEG  (HALO / BLOCK)      // 16 halo elements per thread
#define HVPT  (HSEG / 4)          // 4 float4 per thread for halo
#define DECAY_THR 1e-8f           // fast path iff (1-a)^HALO < this

typedef float f32x4 __attribute__((ext_vector_type(4)));

__device__ __forceinline__ void nt_store4(float* p, float x, float y, float z, float w) {
    f32x4 v = {x, y, z, w};
    __builtin_nontemporal_store(v, (f32x4*)p);
}

// Bank swizzle on float4 index (involution): spreads both access modes
// (lane-contiguous j=t+256k and thread-segment j=t*8+v) uniformly over the
// 8 bank groups (group = pj%8).
__device__ __forceinline__ int sw(int j) { return j ^ ((j >> 3) & 7); }

// x^(2^k) via repeated squaring
__device__ __forceinline__ float pow2k(float x, int k) {
    float p = x;
#pragma unroll
    for (int i = 0; i < k; ++i) p *= p;
    return p;
}

// Inclusive affine scan across the 64 lanes of a wave (shuffle-based).
__device__ __forceinline__ void wave_scan_affine(float& a, float& b) {
    const int lane = threadIdx.x & 63;
#pragma unroll
    for (int off = 1; off < 64; off <<= 1) {
        float pa = __shfl_up(a, off);
        float pb = __shfl_up(b, off);
        if (lane >= off) {
            b = fmaf(a, pb, b);   // later.a * earlier.b + later.b
            a = pa * a;
        }
    }
}

// Block-wide EXCLUSIVE affine scan (identity for t=0). wa/wb: 4-float LDS
// scratch; caller barriers before reuse. Internal barrier between write/read.
__device__ __forceinline__ void block_exscan_affine(
    float a, float b, float* wa, float* wb, int t, float& ea, float& eb)
{
    float ia = a, ib = b;
    wave_scan_affine(ia, ib);                 // inclusive within wave
    const int w = t >> 6, lane = t & 63;
    if (lane == 63) { wa[w] = ia; wb[w] = ib; }
    float xa = __shfl_up(ia, 1);
    float xb = __shfl_up(ib, 1);
    if (lane == 0) { xa = 1.0f; xb = 0.0f; }
    __syncthreads();
    float pa = 1.0f, pb = 0.0f;               // compose waves 0..w-1 in order
#pragma unroll
    for (int i = 0; i < 3; ++i) {
        if (i < w) {
            float ca = wa[i], cb = wb[i];
            pb = fmaf(ca, pb, cb);
            pa *= ca;
        }
    }
    eb = fmaf(xa, pb, xb);                    // combine(wavePrefix, laneExclusive)
    ea = pa * xa;
}

// Pass 1: per-block affine aggregate. Early-exits when the windowed-carry
// fast path applies (aggregates would never be read).
__global__ __launch_bounds__(BLOCK) void k_block_agg(
    const float* __restrict__ y, const float* __restrict__ alpha_p,
    float* __restrict__ aggA, float* __restrict__ aggB, long n)
{
    const float alpha = alpha_p[0];
    const float oma = 1.0f - alpha;
    if (pow2k(oma, 12) < DECAY_THR) return;   // fast path: skip pass 1 entirely

    const int t = threadIdx.x;
    const long base = (long)blockIdx.x * CHUNK + (long)t * SEG;

    float a = 1.0f, s = 0.0f;
    if (base + SEG <= n) {
        const float4* p = (const float4*)(y + base);
#pragma unroll
        for (int v = 0; v < VPT; ++v) {
            float4 q = p[v];
            s = fmaf(oma, s, alpha * q.x);
            s = fmaf(oma, s, alpha * q.y);
            s = fmaf(oma, s, alpha * q.z);
            s = fmaf(oma, s, alpha * q.w);
        }
        a = pow2k(oma, 5);                    // oma^SEG
    } else {
        for (int k = 0; k < SEG; ++k) {
            long idx = base + k;
            if (idx < n) { s = fmaf(oma, s, alpha * y[idx]); a *= oma; }
        }
    }

    __shared__ float wa[4], wb[4];
    wave_scan_affine(a, s);
    if ((t & 63) == 63) { wa[t >> 6] = a; wb[t >> 6] = s; }
    __syncthreads();
    if (t == 0) {
        float ta = 1.0f, tb = 0.0f;
#pragma unroll
        for (int i = 0; i < 4; ++i) {
            float ca = wa[i], cb = wb[i];
            tb = fmaf(ca, tb, cb);
            ta *= ca;
        }
        aggA[blockIdx.x] = ta;
        aggB[blockIdx.x] = tb;
    }
}

// Pass 2: carry from adaptive halo (fast) or aggregate scan (slow); tile
// marshalled through swizzled LDS; cooperative NT stores.
__global__ __launch_bounds__(BLOCK, 4) void k_emit(
    const float* __restrict__ y, const float* __restrict__ alpha_p,
    const float* __restrict__ aggA, const float* __restrict__ aggB,
    float* __restrict__ out, long n, int G)
{
    __shared__ float4 buf[NF4];          // 32 KB tile stage (in, then out)
    __shared__ float wa[4], wb[4];       // exscan wave totals
    __shared__ float hwa[4], hwb[4];     // halo wave totals (separate: no extra barrier)
    __shared__ float s_carry;

    const int t = threadIdx.x;
    // XCD-aware swizzle: consecutive tiles on one XCD. Bijective iff G%8==0.
    int tile = blockIdx.x;
    if ((G & 7) == 0) tile = (tile & 7) * (G >> 3) + (tile >> 3);

    const float alpha = alpha_p[0];
    const float oma   = 1.0f - alpha;
    const bool  fast  = (pow2k(oma, 12) < DECAY_THR);
    const long tbase = (long)tile * CHUNK;
    const long base  = tbase + (long)t * SEG;
    const bool fullTile = (tbase + CHUNK <= n);
    const float y0 = y[0];

    // ---- adaptive halo window W (block-uniform): smallest W with
    //      oma^W <= e^-19.5, clamped to [HSEG, HALO]. fast-gate guarantees
    //      the clamp-to-HALO case still meets the 1e-8 bound. ----
    const bool do_halo = fast && (tile > 0);  // tile>0 => tbase >= CHUNK >= HALO
    int W = HALO;
    if (do_halo) {
        float l = logf(fmaxf(oma, 1e-30f));    // < 0 (fast => oma < 1)
        float wf = -19.5f / l;
        W = (int)ceilf(wf);
        if (W < HSEG) W = HSEG;
        if (W > HALO) W = HALO;
    }
    const bool need = do_halo && ((t + 1) * HSEG > HALO - W);

    // ---- issue halo loads first (independent, long-latency) ----
    float4 hq[HVPT];
    if (need) {
        const float4* hp = (const float4*)(y + (tbase - HALO)) + t * HVPT;
#pragma unroll
        for (int v = 0; v < HVPT; ++v) hq[v] = hp[v];
    }

    // ---- cooperative tile load -> swizzled LDS (lane-contiguous global) ----
    if (fullTile) {
        const float4* p4 = (const float4*)(y + tbase);
        float4 tmp[8];
#pragma unroll
        for (int k = 0; k < 8; ++k) tmp[k] = p4[t + (k << 8)];
#pragma unroll
        for (int k = 0; k < 8; ++k) buf[sw(t + (k << 8))] = tmp[k];
    }

    // ---- halo per-thread reduce + wave scan; totals -> hwa/hwb ----
    if (do_halo) {
        float ha = 1.0f, hs = 0.0f;
        if (need) {                            // skipped threads: exact identity
#pragma unroll
            for (int v = 0; v < HVPT; ++v) {
                float4 q = hq[v];
                hs = fmaf(oma, hs, alpha * q.x);
                hs = fmaf(oma, hs, alpha * q.y);
                hs = fmaf(oma, hs, alpha * q.z);
                hs = fmaf(oma, hs, alpha * q.w);
            }
            ha = pow2k(oma, 4);                // oma^HSEG
        }
        wave_scan_affine(ha, hs);
        if ((t & 63) == 63) { hwa[t >> 6] = ha; hwb[t >> 6] = hs; }
    }

    __syncthreads();   // buf visible; hwa/hwb visible

    // ---- per-thread segment reduce from LDS ----
    float a_seg, b_seg;
    if (fullTile) {
        float s = 0.0f;
#pragma unroll
        for (int v = 0; v < VPT; ++v) {
            float4 q = buf[sw(t * VPT + v)];
            s = fmaf(oma, s, alpha * q.x);
            s = fmaf(oma, s, alpha * q.y);
            s = fmaf(oma, s, alpha * q.z);
            s = fmaf(oma, s, alpha * q.w);
        }
        b_seg = s;
        a_seg = pow2k(oma, 5);                 // oma^SEG
    } else {
        float a = 1.0f, s = 0.0f;
        for (int k = 0; k < SEG; ++k) {
            long idx = base + k;
            if (idx < n) { s = fmaf(oma, s, alpha * y[idx]); a *= oma; }
        }
        a_seg = a; b_seg = s;
    }

    // ---- fold halo wave totals -> carry (a-term <= e^-19.5 dropped) ----
    float carry = y0;                          // exact for tile 0
    if (do_halo) {
        float cb_ = 0.0f;
#pragma unroll
        for (int i = 0; i < 4; ++i) cb_ = fmaf(hwa[i], cb_, hwb[i]);
        carry = cb_;
    }

    // ---- tile exclusive scan (uses wa/wb; internal barrier) ----
    float ea_th, eb_th;
    block_exscan_affine(a_seg, b_seg, wa, wb, t, ea_th, eb_th);

    if (!fast) {
        // ---- slow path: redundant scan of G aggregates -> this tile's carry ----
        const int items = (G + BLOCK - 1) / BLOCK;
        float ta = 1.0f, tb = 0.0f;
        for (int j = 0; j < items; ++j) {
            int g = t * items + j;
            if (g < G) {
                float ca = aggA[g], cb = aggB[g];
                tb = fmaf(ca, tb, cb);
                ta *= ca;
            }
        }
        __syncthreads();                       // wa/wb reads (tile scan) done
        float pa, pb;
        block_exscan_affine(ta, tb, wa, wb, t, pa, pb);
        const int q = tile / items;            // owning thread for this tile's prefix
        if (t == q) {
            float ea = pa, eb = pb;            // aggregates [0, q*items)
            const int r = tile - q * items;    // remaining [q*items, tile)
            for (int j = 0; j < r; ++j) {
                int g = q * items + j;
                float ca = aggA[g], cb = aggB[g];
                eb = fmaf(ca, eb, cb);
                ea *= ca;
            }
            s_carry = fmaf(ea, y0, eb);        // level just before this tile
        }
        __syncthreads();
        carry = s_carry;
    }

    float lvl = fmaf(ea_th, carry, eb_th);     // level just before this segment

    // ---- replay from LDS, write results back in place (own slots only) ----
    if (fullTile) {
#pragma unroll
        for (int v = 0; v < VPT; ++v) {
            const int pj = sw(t * VPT + v);
            float4 q = buf[pj], r;
            lvl = fmaf(oma, lvl, alpha * q.x); r.x = lvl;
            lvl = fmaf(oma, lvl, alpha * q.y); r.y = lvl;
            lvl = fmaf(oma, lvl, alpha * q.z); r.z = lvl;
            lvl = fmaf(oma, lvl, alpha * q.w); r.w = lvl;
            buf[pj] = r;
        }
        __syncthreads();   // all replay writes visible
        // ---- cooperative lane-contiguous NT store (full 64B lines) ----
        const bool lastGuard = (tbase + CHUNK > n - 1);
#pragma unroll
        for (int k = 0; k < 8; ++k) {
            const int j = t + (k << 8);
            float4 r = buf[sw(j)];
            const long gi = tbase + 4L * j;
            if (!lastGuard) {
                nt_store4(out + gi, r.x, r.y, r.z, r.w);
            } else {
                if (gi + 4 <= n - 1) {
                    nt_store4(out + gi, r.x, r.y, r.z, r.w);
                } else {
                    if (gi + 0 < n - 1) out[gi + 0] = r.x;
                    if (gi + 1 < n - 1) out[gi + 1] = r.y;
                    if (gi + 2 < n - 1) out[gi + 2] = r.z;
                    if (gi + 3 < n - 1) out[gi + 3] = r.w;
                }
            }
        }
    } else {
        for (int k = 0; k < SEG; ++k) {
            long idx = base + k;
            if (idx < n) {
                lvl = fmaf(oma, lvl, alpha * y[idx]);
                if (idx < n - 1) out[idx] = lvl;
            }
        }
    }
}

extern "C" void kernel_launch(void* const* d_in, const int* in_sizes, int n_in,
                              void* d_out, int out_size, void* d_ws, size_t ws_size,
                              hipStream_t stream) {
    const float* y     = (const float*)d_in[0];
    const float* alpha = (const float*)d_in[1];
    float* out = (float*)d_out;
    const long n = (long)in_sizes[0];
    const int  G = (int)((n + CHUNK - 1) / CHUNK);   // 2048 for n = 2^24

    float* aggA = (float*)d_ws;        // G floats (written only on slow path)
    float* aggB = aggA + G;            // G floats

    k_block_agg<<<G, BLOCK, 0, stream>>>(y, alpha, aggA, aggB, n);
    k_emit<<<G, BLOCK, 0, stream>>>(y, alpha, aggA, aggB, out, n, G);
}